// Round 3
// baseline (260.476 us; speedup 1.0000x reference)
//
#include <hip/hip_runtime.h>

// Problem constants
#define BB   16
#define CC   16
#define HH   256
#define WW   256
#define HID  128
#define OUTC 13

typedef short short8 __attribute__((ext_vector_type(8)));
typedef float floatx16 __attribute__((ext_vector_type(16)));

__device__ __forceinline__ unsigned short f2bf(float x) {
    unsigned int u = __float_as_uint(x);
    u += 0x7fffu + ((u >> 16) & 1u);          // round-to-nearest-even
    return (unsigned short)(u >> 16);
}

// ws layout: W1F frags [mtG 0..3][tap 0..8][lane 0..63][8 bf16]  = 36864 B
//            W2F frags [s 0..7][lane 0..63][8 bf16]              =  8192 B at +36864
#define W2F_OFF   36864

// ================= prep kernel: bake bf16 weight fragments (R2-validated) ===
__global__ __launch_bounds__(256) void gca_prep(
    const float* __restrict__ w1, const float* __restrict__ w2,
    unsigned char* __restrict__ ws)
{
    const int id = blockIdx.x * 256 + threadIdx.x;   // 2816 total
    const float SX[9] = {-1.f, 0.f, 1.f, -2.f, 0.f, 2.f, -1.f, 0.f, 1.f};
    const float SY[9] = {-1.f, -2.f, -1.f, 0.f, 0.f, 0.f, 1.f, 2.f, 1.f};

    if (id < 2304) {                                  // W1eff frags
        const int mtG  = id / 576;
        const int rem  = id % 576;
        const int tap  = rem / 64;
        const int lane = rem % 64;
        const int p  = lane & 31, hi = lane >> 5;
        const int hid = 32 * mtG + p;
        const float cen = (tap == 4) ? 1.f : 0.f;
        const float sxv = SX[tap], syv = SY[tap];
        const float* wr = w1 + hid * 48;
        unsigned int o[4];
        for (int k = 0; k < 4; ++k) {
            int c0 = 8 * hi + 2 * k;
            float v0 = wr[c0]     * cen + wr[16 + c0]     * sxv + wr[32 + c0]     * syv;
            float v1 = wr[c0 + 1] * cen + wr[16 + c0 + 1] * sxv + wr[32 + c0 + 1] * syv;
            o[k] = (unsigned int)f2bf(v0) | ((unsigned int)f2bf(v1) << 16);
        }
        *(uint4*)(ws + (size_t)id * 16) = make_uint4(o[0], o[1], o[2], o[3]);
    } else if (id < 2816) {                           // W2 (outc padded 13->32) frags
        const int id2 = id - 2304;
        const int s    = id2 / 64;
        const int lane = id2 % 64;
        const int outc = lane & 31, hi = lane >> 5;
        unsigned int o[4];
        for (int k = 0; k < 4; ++k) {
            int hid0 = 16 * s + 8 * hi + 2 * k;
            float v0 = (outc < OUTC) ? w2[outc * HID + hid0]     : 0.f;
            float v1 = (outc < OUTC) ? w2[outc * HID + hid0 + 1] : 0.f;
            o[k] = (unsigned int)f2bf(v0) | ((unsigned int)f2bf(v1) << 16);
        }
        *(uint4*)(ws + W2F_OFF + (size_t)id2 * 16) = make_uint4(o[0], o[1], o[2], o[3]);
    }
}

// ================= main kernel ==============================================
// Block = 4 waves. 8-row x 32-col output tile; halo tile 10x34 pixels x 16c
// bf16 in LDS (pixel stride 10 dw). Wave w owns rows 2w, 2w+1 with ALL 128
// hidden units -> no cross-wave combine, single barrier after staging.
#define TILE_DW 3400   // 10*34*10

__global__ __launch_bounds__(256) void gca_main(
    const float* __restrict__ in,
    const float* __restrict__ b1,
    const unsigned char* __restrict__ ws,
    float* __restrict__ out)
{
    __shared__ unsigned int lds[TILE_DW];

    const int tid  = threadIdx.x;
    const int wid  = tid >> 6;
    const int lane = tid & 63;
    const int p    = lane & 31;    // pixel / n-index
    const int hi   = lane >> 5;    // k-half selector

    const int bI = blockIdx.x >> 8;          // image (16)
    const int rm = blockIdx.x & 255;         // 32 y-tiles x 8 x-tiles
    const int y0 = (rm >> 3) << 3;           // 8-row span
    const int x0 = (rm & 7)  << 5;           // 32-px span

    // ---- stage halo tile (rows y0-1..y0+8, cols x0-1..x0+32), fp32 -> bf16 ----
    {
        unsigned short* tus = (unsigned short*)lds;
        const float* inb = in + ((size_t)bI << 20);
        for (int i = tid; i < 16 * 10 * 34; i += 256) {
            int col = i % 34;
            int rem = i / 34;
            int row = rem % 10;
            int c   = rem / 10;
            int y = (y0 + row - 1) & 255;
            int x = (x0 + col - 1) & 255;
            float v = inb[(c << 16) + (y << 8) + x];
            tus[(row * 34 + col) * 20 + c] = f2bf(v);
        }
    }
    __syncthreads();

#pragma unroll 1
    for (int rr2 = 0; rr2 < 2; ++rr2) {
        const int r   = 2 * wid + rr2;       // local output row 0..7
        const int row = y0 + r;

        // ---- acc init = b1 (reg q of tile mt holds hid 32mt+8q+4hi+{0..3}) ----
        floatx16 acc1[4];
#pragma unroll
        for (int mt = 0; mt < 4; ++mt)
#pragma unroll
            for (int q = 0; q < 4; ++q) {
                float4 bv = *(const float4*)(b1 + 32 * mt + 8 * q + 4 * hi);
                acc1[mt][4 * q + 0] = bv.x;
                acc1[mt][4 * q + 1] = bv.y;
                acc1[mt][4 * q + 2] = bv.z;
                acc1[mt][4 * q + 3] = bv.w;
            }

        // ---- GEMM1: 9 taps, K=16 channels each, 4 hid-tiles ----
#pragma unroll
        for (int tap = 0; tap < 9; ++tap) {
            const int tr  = r + tap / 3;
            const int col = p + tap % 3;
            const int dwo = (tr * 34 + col) * 10 + 4 * hi;
            union { unsigned int u[4]; short8 s; } bfr;
            uint2 lo2 = *(const uint2*)&lds[dwo];
            uint2 hi2 = *(const uint2*)&lds[dwo + 2];
            bfr.u[0] = lo2.x; bfr.u[1] = lo2.y; bfr.u[2] = hi2.x; bfr.u[3] = hi2.y;
#pragma unroll
            for (int mt = 0; mt < 4; ++mt) {
                short8 af = *(const short8*)(ws + (size_t)((mt * 9 + tap) * 64 + lane) * 16);
                acc1[mt] = __builtin_amdgcn_mfma_f32_32x32x16_bf16(af, bfr.s, acc1[mt], 0, 0, 0);
            }
        }

        // ---- relu + pack: hrun[q'] holds hids 8q'+4hi+{0..3} as 4 bf16 ----
        uint2 hrun[16];
#pragma unroll
        for (int mt = 0; mt < 4; ++mt)
#pragma unroll
            for (int q = 0; q < 4; ++q) {
                float h0 = fmaxf(acc1[mt][4 * q + 0], 0.f);
                float h1 = fmaxf(acc1[mt][4 * q + 1], 0.f);
                float h2 = fmaxf(acc1[mt][4 * q + 2], 0.f);
                float h3 = fmaxf(acc1[mt][4 * q + 3], 0.f);
                hrun[4 * mt + q].x = (unsigned int)f2bf(h0) | ((unsigned int)f2bf(h1) << 16);
                hrun[4 * mt + q].y = (unsigned int)f2bf(h2) | ((unsigned int)f2bf(h3) << 16);
            }

        // ---- GEMM2: K=128 over 8 steps; B assembled via half-swap shuffle ----
        floatx16 acc2 = {};
#pragma unroll
        for (int s = 0; s < 8; ++s) {
            uint2 r0 = hrun[2 * s];
            uint2 r1 = hrun[2 * s + 1];
            uint2 x0s, x1s;
            x0s.x = (unsigned int)__shfl_xor((int)r0.x, 32);
            x0s.y = (unsigned int)__shfl_xor((int)r0.y, 32);
            x1s.x = (unsigned int)__shfl_xor((int)r1.x, 32);
            x1s.y = (unsigned int)__shfl_xor((int)r1.y, 32);
            union { unsigned int u[4]; short8 s8; } b2;
            uint2 lo = hi ? x1s : r0;     // k = 16s+8hi+{0..3}
            uint2 hg = hi ? r1  : x0s;    // k = 16s+8hi+{4..7}
            b2.u[0] = lo.x; b2.u[1] = lo.y; b2.u[2] = hg.x; b2.u[3] = hg.y;
            short8 a2 = *(const short8*)(ws + W2F_OFF + (size_t)(s * 64 + lane) * 16);
            acc2 = __builtin_amdgcn_mfma_f32_32x32x16_bf16(a2, b2.s8, acc2, 0, 0, 0);
        }

        // ---- epilogue: residual add ch 3..15, passthrough ch 0..2 ----
#pragma unroll
        for (int reg = 0; reg < 16; ++reg) {
            int oc = (reg & 3) + 8 * (reg >> 2) + 4 * hi;
            if (oc < OUTC) {
                int idx = ((bI * 16 + 3 + oc) << 16) + (row << 8) + x0 + p;
                out[idx] = in[idx] + acc2[reg];
            }
        }
        {
            int c  = lane >> 5;          // 0,1 across the wave
            int idx = ((bI * 16 + c) << 16) + (row << 8) + x0 + p;
            out[idx] = in[idx];
            if (lane < 32) {
                int idx2 = ((bI * 16 + 2) << 16) + (row << 8) + x0 + lane;
                out[idx2] = in[idx2];
            }
        }
    }
}

extern "C" void kernel_launch(void* const* d_in, const int* in_sizes, int n_in,
                              void* d_out, int out_size, void* d_ws, size_t ws_size,
                              hipStream_t stream) {
    const float* x  = (const float*)d_in[0];
    const float* w1 = (const float*)d_in[1];
    const float* b1 = (const float*)d_in[2];
    const float* w2 = (const float*)d_in[3];
    float* out = (float*)d_out;
    unsigned char* ws = (unsigned char*)d_ws;

    hipLaunchKernelGGL(gca_prep, dim3(11), dim3(256), 0, stream, w1, w2, ws);
    hipLaunchKernelGGL(gca_main, dim3(4096), dim3(256), 0, stream, x, b1, ws, out);
}